// Round 1
// baseline (811.577 us; speedup 1.0000x reference)
//
#include <hip/hip_runtime.h>
#include <stdint.h>

#define N_NODES 100000
#define N_EDGES 1000000
#define DIM 64
#define KHOPS 3

// ---------------- workspace layout (bytes) ----------------
// 0        : int flag  (1 = edge_index is int64, 0 = int32)
// 256      : src32  (N_EDGES * 4B = 4 MB)
// +4MB     : dst32  (4 MB)
// +4MB     : dinv   (N_NODES * 4B = 400 KB)
// +512KB   : bufA   (N_NODES*DIM*4 = 25.6 MB)
// +25.6MB  : bufB   (25.6 MB)
// total ~ 60 MB

__global__ void detect_kernel(const void* __restrict__ edges, int* __restrict__ flag) {
    if (blockIdx.x == 0 && threadIdx.x == 0) {
        const long long* e64 = (const long long*)edges;
        int is64 = 1;
        for (int i = 0; i < 8; ++i) {
            long long v = e64[i];
            if (v < 0 || v >= (long long)N_NODES) is64 = 0;
        }
        *flag = is64;
    }
}

__global__ void convert_kernel(const void* __restrict__ edges, const int* __restrict__ flag,
                               int* __restrict__ src, int* __restrict__ dst) {
    int i = blockIdx.x * blockDim.x + threadIdx.x;
    if (i >= 2 * N_EDGES) return;
    int is64 = *flag;
    int v;
    if (is64) v = (int)((const long long*)edges)[i];
    else      v = ((const int*)edges)[i];
    if (i < N_EDGES) src[i] = v;
    else             dst[i - N_EDGES] = v;
}

__global__ void deg_init(float* __restrict__ deg) {
    int i = blockIdx.x * blockDim.x + threadIdx.x;
    if (i < N_NODES) deg[i] = 1.0f;   // self-loop
}

__global__ void deg_accum(const int* __restrict__ dst, float* __restrict__ deg) {
    int e = blockIdx.x * blockDim.x + threadIdx.x;
    if (e < N_EDGES) atomicAdd(&deg[dst[e]], 1.0f);
}

__global__ void deg_finish(float* __restrict__ deg) {
    int i = blockIdx.x * blockDim.x + threadIdx.x;
    if (i < N_NODES) deg[i] = rsqrtf(deg[i]);   // deg >= 1 always
}

// y[i,:] = dinv[i]^2 * x[i,:]   (self-loop contribution; also zero-inits y)
__global__ void hop_init(const float* __restrict__ x, const float* __restrict__ dinv,
                         float* __restrict__ y) {
    int i = blockIdx.x * blockDim.x + threadIdx.x;
    if (i >= N_NODES * DIM) return;
    int node = i >> 6;
    float dv = dinv[node];
    y[i] = dv * dv * x[i];
}

// one 64-lane wave per edge: lane d does dim d
__global__ void hop_edge(const int* __restrict__ src, const int* __restrict__ dst,
                         const float* __restrict__ dinv,
                         const float* __restrict__ x, float* __restrict__ y) {
    int t = blockIdx.x * blockDim.x + threadIdx.x;
    int e = t >> 6;
    if (e >= N_EDGES) return;
    int d = t & 63;
    int s  = src[e];
    int dd = dst[e];
    float norm = dinv[s] * dinv[dd];
    atomicAdd(&y[dd * DIM + d], norm * x[s * DIM + d]);
}

// out = x @ W^T ; thread (ti,j) computes out[row0+ti, j]
__global__ __launch_bounds__(256) void linear_kernel(const float* __restrict__ x,
                                                     const float* __restrict__ W,
                                                     float* __restrict__ out) {
    __shared__ float sW[DIM][DIM + 1];   // +1 pad: (j*65+k)%32 = (j+k)%32 -> 2-way (free)
    __shared__ float sx[4][DIM];
    int tid = threadIdx.x;
    for (int i = tid; i < DIM * DIM; i += 256) sW[i >> 6][i & 63] = W[i];
    int ti = tid >> 6, j = tid & 63;
    int row = blockIdx.x * 4 + ti;
    if (row < N_NODES) sx[ti][j] = x[row * DIM + j];
    __syncthreads();
    if (row >= N_NODES) return;
    float acc = 0.0f;
#pragma unroll
    for (int k = 0; k < DIM; ++k) acc += sx[ti][k] * sW[j][k];
    out[row * DIM + j] = acc;
}

extern "C" void kernel_launch(void* const* d_in, const int* in_sizes, int n_in,
                              void* d_out, int out_size, void* d_ws, size_t ws_size,
                              hipStream_t stream) {
    const float* x     = (const float*)d_in[0];
    const float* W     = (const float*)d_in[1];
    const void*  edges = d_in[2];
    float* out = (float*)d_out;

    char* ws = (char*)d_ws;
    int*   flag  = (int*)ws;
    int*   src32 = (int*)(ws + 256);
    int*   dst32 = (int*)(ws + 256 + (size_t)N_EDGES * 4);
    float* dinv  = (float*)(ws + 256 + (size_t)2 * N_EDGES * 4);
    float* bufA  = (float*)(ws + 256 + (size_t)2 * N_EDGES * 4 + 512 * 1024);
    float* bufB  = bufA + (size_t)N_NODES * DIM;

    detect_kernel<<<1, 64, 0, stream>>>(edges, flag);
    convert_kernel<<<(2 * N_EDGES + 255) / 256, 256, 0, stream>>>(edges, flag, src32, dst32);

    deg_init<<<(N_NODES + 255) / 256, 256, 0, stream>>>(dinv);
    deg_accum<<<(N_EDGES + 255) / 256, 256, 0, stream>>>(dst32, dinv);
    deg_finish<<<(N_NODES + 255) / 256, 256, 0, stream>>>(dinv);

    const float* cur = x;
    float* bufs[2] = {bufA, bufB};
    for (int k = 0; k < KHOPS; ++k) {
        float* y = bufs[k & 1];
        hop_init<<<(N_NODES * DIM + 255) / 256, 256, 0, stream>>>(cur, dinv, y);
        hop_edge<<<((size_t)N_EDGES * 64 + 255) / 256, 256, 0, stream>>>(src32, dst32, dinv, cur, y);
        cur = y;
    }

    linear_kernel<<<(N_NODES + 3) / 4, 256, 0, stream>>>(cur, W, out);
}

// Round 2
// 475.689 us; speedup vs baseline: 1.7061x; 1.7061x over previous
//
#include <hip/hip_runtime.h>
#include <stdint.h>

#define N_NODES 100000
#define N_EDGES 1000000
#define DIM 64
#define KHOPS 3

// ---------------- workspace layout (bytes) ----------------
// 0        : int flag (1 = edges are int64)
// 1024     : blocksum[512] ints (scan aux)
// 8192     : dinv   (400 KB)
// +512KB   : cnt    (N ints; reused as scatter cursor)
// +512KB   : rowptr (N+1 ints)
// +512KB   : csr_src (N_EDGES ints = 4 MB)
// +4MB     : bufA (25.6 MB)
// +25.6MB  : bufB (25.6 MB)
// total ~ 57 MB (same footprint as round 1)

__device__ __forceinline__ int load_src(const void* edges, int is64, int e) {
    // int64 edge values are < 2^31, little-endian: low dword suffices
    return is64 ? ((const int*)edges)[2 * e] : ((const int*)edges)[e];
}
__device__ __forceinline__ int load_dst(const void* edges, int is64, int e) {
    return is64 ? ((const int*)edges)[2 * (N_EDGES + e)] : ((const int*)edges)[N_EDGES + e];
}

__global__ void detect_kernel(const void* __restrict__ edges, int* __restrict__ flag) {
    if (blockIdx.x == 0 && threadIdx.x == 0) {
        const long long* e64 = (const long long*)edges;
        int is64 = 1;
        for (int i = 0; i < 8; ++i) {
            long long v = e64[i];
            if (v < 0 || v >= (long long)N_NODES) is64 = 0;
        }
        *flag = is64;
    }
}

__global__ void zero_cnt(int* __restrict__ cnt) {
    int i = blockIdx.x * blockDim.x + threadIdx.x;
    if (i < N_NODES) cnt[i] = 0;
}

__global__ void count_kernel(const void* __restrict__ edges, const int* __restrict__ flag,
                             int* __restrict__ cnt) {
    int e = blockIdx.x * blockDim.x + threadIdx.x;
    if (e >= N_EDGES) return;
    int is64 = *flag;
    atomicAdd(&cnt[load_dst(edges, is64, e)], 1);
}

__global__ void dinv_kernel(const int* __restrict__ cnt, float* __restrict__ dinv) {
    int i = blockIdx.x * blockDim.x + threadIdx.x;
    if (i < N_NODES) dinv[i] = rsqrtf((float)(cnt[i] + 1));  // +1 self-loop
}

// ---- 3-kernel exclusive scan of cnt[N] -> rowptr[N+1] ----
__global__ void scan1(const int* __restrict__ cnt, int* __restrict__ rowptr,
                      int* __restrict__ blocksum) {
    __shared__ int tmp[256];
    int t = threadIdx.x;
    int i = blockIdx.x * 256 + t;
    int v = (i < N_NODES) ? cnt[i] : 0;
    tmp[t] = v;
    __syncthreads();
    for (int off = 1; off < 256; off <<= 1) {
        int a = (t >= off) ? tmp[t - off] : 0;
        __syncthreads();
        tmp[t] += a;
        __syncthreads();
    }
    if (i < N_NODES) rowptr[i] = tmp[t] - v;   // exclusive
    if (t == 255) blocksum[blockIdx.x] = tmp[255];
}

__global__ void scan2(int* __restrict__ blocksum, int nblocks) {
    __shared__ int tmp[512];
    int t = threadIdx.x;
    int v = (t < nblocks) ? blocksum[t] : 0;
    tmp[t] = v;
    __syncthreads();
    for (int off = 1; off < 512; off <<= 1) {
        int a = (t >= off) ? tmp[t - off] : 0;
        __syncthreads();
        tmp[t] += a;
        __syncthreads();
    }
    if (t < nblocks) blocksum[t] = tmp[t] - v;  // exclusive
}

__global__ void scan3(int* __restrict__ rowptr, const int* __restrict__ blocksum) {
    int i = blockIdx.x * blockDim.x + threadIdx.x;
    if (i < N_NODES) rowptr[i] += blocksum[i >> 8];
    if (i == N_NODES) rowptr[N_NODES] = N_EDGES;
}

// scatter edges into CSC slots; consumes cnt as a countdown cursor
__global__ void scatter_kernel(const void* __restrict__ edges, const int* __restrict__ flag,
                               const int* __restrict__ rowptr, int* __restrict__ cnt,
                               int* __restrict__ csr_src) {
    int e = blockIdx.x * blockDim.x + threadIdx.x;
    if (e >= N_EDGES) return;
    int is64 = *flag;
    int s = load_src(edges, is64, e);
    int d = load_dst(edges, is64, e);
    int pos = rowptr[d] + atomicSub(&cnt[d], 1) - 1;
    csr_src[pos] = s;
}

// one 64-lane wave per node: lane d accumulates dim d over incoming edges
__global__ __launch_bounds__(256) void hop_kernel(const float* __restrict__ xin,
                                                  const int* __restrict__ rowptr,
                                                  const int* __restrict__ csr_src,
                                                  const float* __restrict__ dinv,
                                                  float* __restrict__ y) {
    int t = blockIdx.x * blockDim.x + threadIdx.x;
    int n = t >> 6;
    if (n >= N_NODES) return;
    int d = t & 63;
    float dn = dinv[n];
    float acc = dn * xin[n * DIM + d];          // self-loop (dinv[n]^2 after final scale)
    int beg = rowptr[n], end = rowptr[n + 1];
    for (int j = beg; j < end; ++j) {
        int s = csr_src[j];                     // wave-broadcast load
        acc += dinv[s] * xin[s * DIM + d];      // coalesced 256B gather
    }
    y[n * DIM + d] = dn * acc;
}

// out = x @ W^T
__global__ __launch_bounds__(256) void linear_kernel(const float* __restrict__ x,
                                                     const float* __restrict__ W,
                                                     float* __restrict__ out) {
    __shared__ float sW[DIM][DIM + 1];
    __shared__ float sx[4][DIM];
    int tid = threadIdx.x;
    for (int i = tid; i < DIM * DIM; i += 256) sW[i >> 6][i & 63] = W[i];
    int ti = tid >> 6, j = tid & 63;
    int row = blockIdx.x * 4 + ti;
    if (row < N_NODES) sx[ti][j] = x[row * DIM + j];
    __syncthreads();
    if (row >= N_NODES) return;
    float acc = 0.0f;
#pragma unroll
    for (int k = 0; k < DIM; ++k) acc += sx[ti][k] * sW[j][k];
    out[row * DIM + j] = acc;
}

extern "C" void kernel_launch(void* const* d_in, const int* in_sizes, int n_in,
                              void* d_out, int out_size, void* d_ws, size_t ws_size,
                              hipStream_t stream) {
    const float* x     = (const float*)d_in[0];
    const float* W     = (const float*)d_in[1];
    const void*  edges = d_in[2];
    float* out = (float*)d_out;

    char* ws = (char*)d_ws;
    int*   flag     = (int*)ws;
    int*   blocksum = (int*)(ws + 1024);
    float* dinv     = (float*)(ws + 8192);
    char*  p        = ws + 8192 + 512 * 1024;
    int*   cnt      = (int*)p;            p += 512 * 1024;
    int*   rowptr   = (int*)p;            p += 512 * 1024;
    int*   csr_src  = (int*)p;            p += (size_t)N_EDGES * 4;
    float* bufA     = (float*)p;
    float* bufB     = bufA + (size_t)N_NODES * DIM;

    const int EB = (N_EDGES + 255) / 256;       // edge-parallel blocks
    const int NB = (N_NODES + 255) / 256;       // node-parallel blocks
    const int SB = (N_NODES + 255) / 256;       // scan blocks (391)

    detect_kernel<<<1, 64, 0, stream>>>(edges, flag);
    zero_cnt<<<NB, 256, 0, stream>>>(cnt);
    count_kernel<<<EB, 256, 0, stream>>>(edges, flag, cnt);
    dinv_kernel<<<NB, 256, 0, stream>>>(cnt, dinv);
    scan1<<<SB, 256, 0, stream>>>(cnt, rowptr, blocksum);
    scan2<<<1, 512, 0, stream>>>(blocksum, SB);
    scan3<<<(N_NODES + 256) / 256, 256, 0, stream>>>(rowptr, blocksum);
    scatter_kernel<<<EB, 256, 0, stream>>>(edges, flag, rowptr, cnt, csr_src);

    const float* cur = x;
    float* bufs[2] = {bufA, bufB};
    for (int k = 0; k < KHOPS; ++k) {
        float* y = bufs[k & 1];
        hop_kernel<<<(N_NODES * 64 + 255) / 256, 256, 0, stream>>>(cur, rowptr, csr_src, dinv, y);
        cur = y;
    }

    linear_kernel<<<(N_NODES + 3) / 4, 256, 0, stream>>>(cur, W, out);
}

// Round 3
// 329.221 us; speedup vs baseline: 2.4651x; 1.4449x over previous
//
#include <hip/hip_runtime.h>
#include <stdint.h>

#define N_NODES 100000
#define N_EDGES 1000000
#define DIM 64
#define KHOPS 3

// ---------------- workspace layout (bytes) ----------------
// 0        : int flag (1 = edges are int64)
// 1024     : blocksum[512] ints (scan aux)
// 8192     : dinv   (400 KB)
// +512KB   : cnt    (N ints; reused as scatter cursor)
// +512KB   : rowptr (N+1 ints)
// +512KB   : csr_src (N_EDGES ints = 4 MB)
// +4MB     : bufA (25.6 MB)
// +25.6MB  : bufB (25.6 MB)

__device__ __forceinline__ int load_src(const void* edges, int is64, int e) {
    return is64 ? ((const int*)edges)[2 * e] : ((const int*)edges)[e];
}
__device__ __forceinline__ int load_dst(const void* edges, int is64, int e) {
    return is64 ? ((const int*)edges)[2 * (N_EDGES + e)] : ((const int*)edges)[N_EDGES + e];
}

__global__ void detect_kernel(const void* __restrict__ edges, int* __restrict__ flag) {
    if (blockIdx.x == 0 && threadIdx.x == 0) {
        const long long* e64 = (const long long*)edges;
        int is64 = 1;
        for (int i = 0; i < 8; ++i) {
            long long v = e64[i];
            if (v < 0 || v >= (long long)N_NODES) is64 = 0;
        }
        *flag = is64;
    }
}

__global__ void zero_cnt(int* __restrict__ cnt) {
    int i = blockIdx.x * blockDim.x + threadIdx.x;
    if (i < N_NODES) cnt[i] = 0;
}

__global__ void count_kernel(const void* __restrict__ edges, const int* __restrict__ flag,
                             int* __restrict__ cnt) {
    int e = blockIdx.x * blockDim.x + threadIdx.x;
    if (e >= N_EDGES) return;
    int is64 = *flag;
    atomicAdd(&cnt[load_dst(edges, is64, e)], 1);
}

__global__ void dinv_kernel(const int* __restrict__ cnt, float* __restrict__ dinv) {
    int i = blockIdx.x * blockDim.x + threadIdx.x;
    if (i < N_NODES) dinv[i] = rsqrtf((float)(cnt[i] + 1));  // +1 self-loop
}

// ---- 3-kernel exclusive scan of cnt[N] -> rowptr[N+1] ----
__global__ void scan1(const int* __restrict__ cnt, int* __restrict__ rowptr,
                      int* __restrict__ blocksum) {
    __shared__ int tmp[256];
    int t = threadIdx.x;
    int i = blockIdx.x * 256 + t;
    int v = (i < N_NODES) ? cnt[i] : 0;
    tmp[t] = v;
    __syncthreads();
    for (int off = 1; off < 256; off <<= 1) {
        int a = (t >= off) ? tmp[t - off] : 0;
        __syncthreads();
        tmp[t] += a;
        __syncthreads();
    }
    if (i < N_NODES) rowptr[i] = tmp[t] - v;   // exclusive
    if (t == 255) blocksum[blockIdx.x] = tmp[255];
}

__global__ void scan2(int* __restrict__ blocksum, int nblocks) {
    __shared__ int tmp[512];
    int t = threadIdx.x;
    int v = (t < nblocks) ? blocksum[t] : 0;
    tmp[t] = v;
    __syncthreads();
    for (int off = 1; off < 512; off <<= 1) {
        int a = (t >= off) ? tmp[t - off] : 0;
        __syncthreads();
        tmp[t] += a;
        __syncthreads();
    }
    if (t < nblocks) blocksum[t] = tmp[t] - v;  // exclusive
}

__global__ void scan3(int* __restrict__ rowptr, const int* __restrict__ blocksum) {
    int i = blockIdx.x * blockDim.x + threadIdx.x;
    if (i < N_NODES) rowptr[i] += blocksum[i >> 8];
    if (i == N_NODES) rowptr[N_NODES] = N_EDGES;
}

__global__ void scatter_kernel(const void* __restrict__ edges, const int* __restrict__ flag,
                               const int* __restrict__ rowptr, int* __restrict__ cnt,
                               int* __restrict__ csr_src) {
    int e = blockIdx.x * blockDim.x + threadIdx.x;
    if (e >= N_EDGES) return;
    int is64 = *flag;
    int s = load_src(edges, is64, e);
    int d = load_dst(edges, is64, e);
    int pos = rowptr[d] + atomicSub(&cnt[d], 1) - 1;
    csr_src[pos] = s;
}

// v0 = dinv * x  (row-scaled input)
__global__ void vinit_kernel(const float* __restrict__ x, const float* __restrict__ dinv,
                             float* __restrict__ v) {
    int i = blockIdx.x * blockDim.x + threadIdx.x;
    if (i >= N_NODES * DIM) return;
    v[i] = dinv[i >> 6] * x[i];
}

// v' [n] = scale * (v[n] + sum_{s in in(n)} v[s]);  scale = dinv^2 (mid) or dinv (final)
// one 64-lane wave per node, 4-wide padded unroll for MLP
template <int FINAL>
__global__ __launch_bounds__(256) void hop_kernel(const float* __restrict__ v,
                                                  const int* __restrict__ rowptr,
                                                  const int* __restrict__ csr_src,
                                                  const float* __restrict__ dinv,
                                                  float* __restrict__ y) {
    int t = blockIdx.x * blockDim.x + threadIdx.x;
    int n = t >> 6;
    if (n >= N_NODES) return;
    int d = t & 63;
    int beg = rowptr[n], end = rowptr[n + 1];
    float acc = v[n * DIM + d];                  // self-loop term
    for (int j = beg; j < end; j += 4) {
        int j1 = min(j + 1, end - 1);
        int j2 = min(j + 2, end - 1);
        int j3 = min(j + 3, end - 1);
        int s0 = csr_src[j];                     // wave-broadcast loads
        int s1 = csr_src[j1];
        int s2 = csr_src[j2];
        int s3 = csr_src[j3];
        float g0 = v[s0 * DIM + d];              // 4 independent 256B gathers
        float g1 = v[s1 * DIM + d];
        float g2 = v[s2 * DIM + d];
        float g3 = v[s3 * DIM + d];
        acc += g0;
        acc += (j + 1 < end) ? g1 : 0.0f;
        acc += (j + 2 < end) ? g2 : 0.0f;
        acc += (j + 3 < end) ? g3 : 0.0f;
    }
    float dn = dinv[n];
    float scale = FINAL ? dn : dn * dn;
    y[n * DIM + d] = scale * acc;
}

// out = x @ W^T
__global__ __launch_bounds__(256) void linear_kernel(const float* __restrict__ x,
                                                     const float* __restrict__ W,
                                                     float* __restrict__ out) {
    __shared__ float sW[DIM][DIM + 1];
    __shared__ float sx[4][DIM];
    int tid = threadIdx.x;
    for (int i = tid; i < DIM * DIM; i += 256) sW[i >> 6][i & 63] = W[i];
    int ti = tid >> 6, j = tid & 63;
    int row = blockIdx.x * 4 + ti;
    if (row < N_NODES) sx[ti][j] = x[row * DIM + j];
    __syncthreads();
    if (row >= N_NODES) return;
    float acc = 0.0f;
#pragma unroll
    for (int k = 0; k < DIM; ++k) acc += sx[ti][k] * sW[j][k];
    out[row * DIM + j] = acc;
}

extern "C" void kernel_launch(void* const* d_in, const int* in_sizes, int n_in,
                              void* d_out, int out_size, void* d_ws, size_t ws_size,
                              hipStream_t stream) {
    const float* x     = (const float*)d_in[0];
    const float* W     = (const float*)d_in[1];
    const void*  edges = d_in[2];
    float* out = (float*)d_out;

    char* ws = (char*)d_ws;
    int*   flag     = (int*)ws;
    int*   blocksum = (int*)(ws + 1024);
    float* dinv     = (float*)(ws + 8192);
    char*  p        = ws + 8192 + 512 * 1024;
    int*   cnt      = (int*)p;            p += 512 * 1024;
    int*   rowptr   = (int*)p;            p += 512 * 1024;
    int*   csr_src  = (int*)p;            p += (size_t)N_EDGES * 4;
    float* bufA     = (float*)p;
    float* bufB     = bufA + (size_t)N_NODES * DIM;

    const int EB = (N_EDGES + 255) / 256;
    const int NB = (N_NODES + 255) / 256;
    const int SB = (N_NODES + 255) / 256;

    detect_kernel<<<1, 64, 0, stream>>>(edges, flag);
    zero_cnt<<<NB, 256, 0, stream>>>(cnt);
    count_kernel<<<EB, 256, 0, stream>>>(edges, flag, cnt);
    dinv_kernel<<<NB, 256, 0, stream>>>(cnt, dinv);
    scan1<<<SB, 256, 0, stream>>>(cnt, rowptr, blocksum);
    scan2<<<1, 512, 0, stream>>>(blocksum, SB);
    scan3<<<(N_NODES + 256) / 256, 256, 0, stream>>>(rowptr, blocksum);
    scatter_kernel<<<EB, 256, 0, stream>>>(edges, flag, rowptr, cnt, csr_src);

    // v0 = dinv * x
    vinit_kernel<<<(N_NODES * DIM + 255) / 256, 256, 0, stream>>>(x, dinv, bufA);

    // hop 1: bufA -> bufB ; hop 2: bufB -> bufA ; hop 3 (final scale): bufA -> bufB
    const int HB = (N_NODES * 64 + 255) / 256;
    hop_kernel<0><<<HB, 256, 0, stream>>>(bufA, rowptr, csr_src, dinv, bufB);
    hop_kernel<0><<<HB, 256, 0, stream>>>(bufB, rowptr, csr_src, dinv, bufA);
    hop_kernel<1><<<HB, 256, 0, stream>>>(bufA, rowptr, csr_src, dinv, bufB);

    linear_kernel<<<(N_NODES + 3) / 4, 256, 0, stream>>>(bufB, W, out);
}

// Round 4
// 290.547 us; speedup vs baseline: 2.7933x; 1.1331x over previous
//
#include <hip/hip_runtime.h>
#include <stdint.h>

#define N_NODES 100000
#define N_EDGES 1000000
#define DIM 64
#define MAXD 32                 // ELL width; 128B per row (one line pair)
#define SENT N_NODES            // sentinel index -> zero row in v buffers
#define OVF_CAP 65536
#define ELL_INTS (N_NODES * MAXD)

__device__ __forceinline__ int load_src(const void* edges, int is64, int e) {
    if (is64) return ((const int2*)edges)[e].x;          // int64 values < 2^31
    return ((const int*)edges)[e];
}
__device__ __forceinline__ int load_dst(const void* edges, int is64, int e) {
    if (is64) return ((const int2*)edges)[N_EDGES + e].x;
    return ((const int*)edges)[N_EDGES + e];
}

__global__ void detect_kernel(const void* __restrict__ edges, int* __restrict__ flag) {
    if (blockIdx.x == 0 && threadIdx.x == 0) {
        const long long* e64 = (const long long*)edges;
        int is64 = 1;
        for (int i = 0; i < 8; ++i) {
            long long v = e64[i];
            if (v < 0 || v >= (long long)N_NODES) is64 = 0;
        }
        *flag = is64;
    }
}

// zero cnt + ovf_cnt, fill ELL with sentinel, zero sentinel row of both v-buffers
__global__ void init_kernel(int* __restrict__ cnt, int* __restrict__ ovf_cnt,
                            int* __restrict__ ell,
                            float* __restrict__ bufA, float* __restrict__ bufB) {
    int i = blockIdx.x * blockDim.x + threadIdx.x;
    if (i < ELL_INTS) ell[i] = SENT;
    if (i < N_NODES) cnt[i] = 0;
    if (i == 0) *ovf_cnt = 0;
    if (i < DIM) {
        bufA[(size_t)SENT * DIM + i] = 0.0f;
        bufB[(size_t)SENT * DIM + i] = 0.0f;
    }
}

// one-pass ELL build: k = cursor++, slot write; overflow -> list
__global__ void scatter_ell(const void* __restrict__ edges, const int* __restrict__ flag,
                            int* __restrict__ cnt, int* __restrict__ ell,
                            int2* __restrict__ ovf, int* __restrict__ ovf_cnt) {
    int e = blockIdx.x * blockDim.x + threadIdx.x;
    if (e >= N_EDGES) return;
    int is64 = *flag;
    int s = load_src(edges, is64, e);
    int d = load_dst(edges, is64, e);
    int k = atomicAdd(&cnt[d], 1);
    if (k < MAXD) {
        ell[d * MAXD + k] = s;
    } else {
        int o = atomicAdd(ovf_cnt, 1);
        if (o < OVF_CAP) ovf[o] = make_int2(s, d);
    }
}

__global__ void dinv_kernel(const int* __restrict__ cnt, float* __restrict__ dinv) {
    int i = blockIdx.x * blockDim.x + threadIdx.x;
    if (i < N_NODES) dinv[i] = rsqrtf((float)(cnt[i] + 1));  // true degree + self-loop
}

// v0 = dinv * x  (row-scaled input); sentinel row zeroed by init_kernel
__global__ void vinit_kernel(const float* __restrict__ x, const float* __restrict__ dinv,
                             float* __restrict__ v) {
    int i = blockIdx.x * blockDim.x + threadIdx.x;
    if (i >= N_NODES * DIM) return;
    v[i] = dinv[i >> 6] * x[i];
}

// v'[n] = scale * (v[n] + sum_in v[s]); scale = dinv^2 (mid) or dinv (final)
// one wave per node; ELL row loaded once, indices broadcast via shfl;
// deg padded to x4 with sentinel (zero row) -> branch-free inner loop
template <int FINAL>
__global__ __launch_bounds__(256) void hop_kernel(const float* __restrict__ v,
                                                  const int* __restrict__ cnt,
                                                  const int* __restrict__ ell,
                                                  const float* __restrict__ dinv,
                                                  float* __restrict__ y) {
    int t = blockIdx.x * blockDim.x + threadIdx.x;
    int n = t >> 6;
    if (n >= N_NODES) return;
    int d = t & 63;
    int deg = cnt[n];                    // wave-uniform broadcast load
    if (deg > MAXD) deg = MAXD;
    int deg4 = (deg + 3) & ~3;
    int idx = ell[(n << 5) + (d & 31)];  // 128B coalesced row load
    float acc = v[n * DIM + d];          // self-loop term
    for (int j = 0; j < deg4; j += 4) {  // j+3 <= 31 always
        int s0 = __shfl(idx, j, 64);
        int s1 = __shfl(idx, j + 1, 64);
        int s2 = __shfl(idx, j + 2, 64);
        int s3 = __shfl(idx, j + 3, 64);
        float g0 = v[s0 * DIM + d];
        float g1 = v[s1 * DIM + d];
        float g2 = v[s2 * DIM + d];
        float g3 = v[s3 * DIM + d];
        acc += g0 + g1 + g2 + g3;
    }
    float dn = dinv[n];
    y[n * DIM + d] = (FINAL ? dn : dn * dn) * acc;
}

// rare overflow edges (true degree > MAXD): atomic fixup after each hop
template <int FINAL>
__global__ void ovf_fix(const int2* __restrict__ ovf, const int* __restrict__ ovf_cnt,
                        const float* __restrict__ v, const float* __restrict__ dinv,
                        float* __restrict__ y) {
    int m = *ovf_cnt;
    if (m > OVF_CAP) m = OVF_CAP;
    int total = m * DIM;
    for (int i = blockIdx.x * blockDim.x + threadIdx.x; i < total;
         i += gridDim.x * blockDim.x) {
        int e = i >> 6, d = i & 63;
        int s = ovf[e].x, n = ovf[e].y;
        float dn = dinv[n];
        float sc = FINAL ? dn : dn * dn;
        atomicAdd(&y[n * DIM + d], sc * v[s * DIM + d]);
    }
}

// out = x @ W^T
__global__ __launch_bounds__(256) void linear_kernel(const float* __restrict__ x,
                                                     const float* __restrict__ W,
                                                     float* __restrict__ out) {
    __shared__ float sW[DIM][DIM + 1];
    __shared__ float sx[4][DIM];
    int tid = threadIdx.x;
    for (int i = tid; i < DIM * DIM; i += 256) sW[i >> 6][i & 63] = W[i];
    int ti = tid >> 6, j = tid & 63;
    int row = blockIdx.x * 4 + ti;
    if (row < N_NODES) sx[ti][j] = x[row * DIM + j];
    __syncthreads();
    if (row >= N_NODES) return;
    float acc = 0.0f;
#pragma unroll
    for (int k = 0; k < DIM; ++k) acc += sx[ti][k] * sW[j][k];
    out[row * DIM + j] = acc;
}

extern "C" void kernel_launch(void* const* d_in, const int* in_sizes, int n_in,
                              void* d_out, int out_size, void* d_ws, size_t ws_size,
                              hipStream_t stream) {
    const float* x     = (const float*)d_in[0];
    const float* W     = (const float*)d_in[1];
    const void*  edges = d_in[2];
    float* out = (float*)d_out;

    char* ws = (char*)d_ws;
    int*   flag    = (int*)ws;
    int*   ovf_cnt = (int*)(ws + 4);
    float* dinv    = (float*)(ws + 8192);
    char*  p       = ws + 8192 + 512 * 1024;
    int*   cnt     = (int*)p;   p += 512 * 1024;
    int*   ell     = (int*)p;   p += (size_t)ELL_INTS * 4;     // 12.8 MB
    int2*  ovf     = (int2*)p;  p += (size_t)OVF_CAP * 8;      // 512 KB
    float* bufA    = (float*)p; p += (size_t)(N_NODES + 1) * DIM * 4;
    float* bufB    = (float*)p;

    const int EB = (N_EDGES + 255) / 256;
    const int NB = (N_NODES + 255) / 256;
    const int IB = (ELL_INTS + 255) / 256;
    const int HB = (N_NODES * 64 + 255) / 256;

    detect_kernel<<<1, 64, 0, stream>>>(edges, flag);
    init_kernel<<<IB, 256, 0, stream>>>(cnt, ovf_cnt, ell, bufA, bufB);
    scatter_ell<<<EB, 256, 0, stream>>>(edges, flag, cnt, ell, ovf, ovf_cnt);
    dinv_kernel<<<NB, 256, 0, stream>>>(cnt, dinv);
    vinit_kernel<<<(N_NODES * DIM + 255) / 256, 256, 0, stream>>>(x, dinv, bufA);

    // hop1: A->B, hop2: B->A, hop3(final): A->B
    hop_kernel<0><<<HB, 256, 0, stream>>>(bufA, cnt, ell, dinv, bufB);
    ovf_fix<0><<<32, 256, 0, stream>>>(ovf, ovf_cnt, bufA, dinv, bufB);
    hop_kernel<0><<<HB, 256, 0, stream>>>(bufB, cnt, ell, dinv, bufA);
    ovf_fix<0><<<32, 256, 0, stream>>>(ovf, ovf_cnt, bufB, dinv, bufA);
    hop_kernel<1><<<HB, 256, 0, stream>>>(bufA, cnt, ell, dinv, bufB);
    ovf_fix<1><<<32, 256, 0, stream>>>(ovf, ovf_cnt, bufA, dinv, bufB);

    linear_kernel<<<(N_NODES + 3) / 4, 256, 0, stream>>>(bufB, W, out);
}